// Round 5
// baseline (862.449 us; speedup 1.0000x reference)
//
#include <hip/hip_runtime.h>
#include <hip/hip_bf16.h>

#define DD 64
#define SCAN_CH 1024

typedef __attribute__((ext_vector_type(8))) short bf16x8;
typedef __attribute__((ext_vector_type(4))) float f32x4;

__device__ __forceinline__ unsigned short f2bf(float f) {
    unsigned int u = __float_as_uint(f);
    unsigned int r = (u + 0x7fffu + ((u >> 16) & 1u)) >> 16;   // RNE
    return (unsigned short)r;
}
__device__ __forceinline__ float bf2f(unsigned short u) {
    return __uint_as_float((unsigned int)u << 16);
}
__device__ __forceinline__ unsigned int pack2(float lo, float hi) {
    return (unsigned int)f2bf(lo) | ((unsigned int)f2bf(hi) << 16);
}
__device__ __forceinline__ void pk_atomic_add_bf16(unsigned short* addr, unsigned int data) {
    asm volatile("global_atomic_pk_add_bf16 %0, %1, off" :: "v"(addr), "v"(data) : "memory");
}

// B frag for 16x16x32: lane l holds B[k = ks*32 + (l>>4)*8 + b][col = nt*16 + (l&15)]
__device__ __forceinline__ void load_w_frags(const float* __restrict__ W, int lane,
                                             bf16x8 bw[4][2]) {
    const int kl = (lane >> 4) * 8;
    const int cl = lane & 15;
#pragma unroll
    for (int nt = 0; nt < 4; ++nt)
#pragma unroll
        for (int ks = 0; ks < 2; ++ks)
#pragma unroll
            for (int b = 0; b < 8; ++b)
                bw[nt][ks][b] = (short)f2bf(W[(ks * 32 + kl + b) * DD + nt * 16 + cl]);
}

#define MFMA8(A0, A1)                                                          \
    acc0 = __builtin_amdgcn_mfma_f32_16x16x32_bf16(A0, bw[0][0], acc0, 0, 0, 0); \
    acc0 = __builtin_amdgcn_mfma_f32_16x16x32_bf16(A1, bw[0][1], acc0, 0, 0, 0); \
    acc1 = __builtin_amdgcn_mfma_f32_16x16x32_bf16(A0, bw[1][0], acc1, 0, 0, 0); \
    acc1 = __builtin_amdgcn_mfma_f32_16x16x32_bf16(A1, bw[1][1], acc1, 0, 0, 0); \
    acc2 = __builtin_amdgcn_mfma_f32_16x16x32_bf16(A0, bw[2][0], acc2, 0, 0, 0); \
    acc2 = __builtin_amdgcn_mfma_f32_16x16x32_bf16(A1, bw[2][1], acc2, 0, 0, 0); \
    acc3 = __builtin_amdgcn_mfma_f32_16x16x32_bf16(A0, bw[3][0], acc3, 0, 0, 0); \
    acc3 = __builtin_amdgcn_mfma_f32_16x16x32_bf16(A1, bw[3][1], acc3, 0, 0, 0);

// ---------- shared: x-table prep ----------
__global__ __launch_bounds__(256) void xprep_kernel(
    const float4* __restrict__ feat4, const float4* __restrict__ emb4,
    const int* __restrict__ rel, unsigned short* __restrict__ xtab, int n4) {
    int i = blockIdx.x * blockDim.x + threadIdx.x;
    const int stride = gridDim.x * blockDim.x;
    for (; i < n4; i += stride) {
        const int e  = i >> 4;
        const int re = rel[e];
        const float4 f = feat4[i];
        const float4 g = emb4[re * 16 + (i & 15)];
        ushort4 o;
        o.x = f2bf(f.x + g.x); o.y = f2bf(f.y + g.y);
        o.z = f2bf(f.z + g.z); o.w = f2bf(f.w + g.w);
        *reinterpret_cast<ushort4*>(&xtab[(size_t)i * 4]) = o;
    }
}

// ---------- tier 3: sorted-CSR atomic-free path ----------

__global__ __launch_bounds__(256) void hist_kernel(const int* __restrict__ ac,
                                                   unsigned int* __restrict__ cnt, int T_) {
    int t = blockIdx.x * blockDim.x + threadIdx.x;
    const int stride = gridDim.x * blockDim.x;
    for (; t < T_; t += stride) atomicAdd(&cnt[ac[t]], 1u);
}

__global__ __launch_bounds__(256) void scanA_kernel(const unsigned int* __restrict__ cnt,
                                                    unsigned int* __restrict__ bsum, int n) {
    __shared__ unsigned int s[256];
    const int b = blockIdx.x, tid = threadIdx.x;
    const int base = b * SCAN_CH + tid * 4;
    unsigned int v = 0;
#pragma unroll
    for (int k = 0; k < 4; ++k) { const int i = base + k; if (i < n) v += cnt[i]; }
    s[tid] = v; __syncthreads();
    for (int off = 128; off > 0; off >>= 1) {
        if (tid < off) s[tid] += s[tid + off];
        __syncthreads();
    }
    if (tid == 0) bsum[b] = s[0];
}

__global__ __launch_bounds__(1024) void scanB_kernel(unsigned int* bsum, int nb) {
    __shared__ unsigned int s[1024];
    const int tid = threadIdx.x;
    s[tid] = (tid < nb) ? bsum[tid] : 0u;
    __syncthreads();
    for (int off = 1; off < 1024; off <<= 1) {
        const unsigned int t = (tid >= off) ? s[tid - off] : 0u;
        __syncthreads();
        s[tid] += t;
        __syncthreads();
    }
    if (tid < nb) bsum[tid] = (tid == 0) ? 0u : s[tid - 1];   // exclusive
}

__global__ __launch_bounds__(256) void scanC_kernel(const unsigned int* __restrict__ cnt,
                                                    const unsigned int* __restrict__ bsum,
                                                    unsigned int* __restrict__ offs, int n) {
    __shared__ unsigned int s[256];
    const int b = blockIdx.x, tid = threadIdx.x;
    const int base = b * SCAN_CH + tid * 4;
    unsigned int v[4], sum = 0;
#pragma unroll
    for (int k = 0; k < 4; ++k) { const int i = base + k; v[k] = (i < n) ? cnt[i] : 0u; sum += v[k]; }
    s[tid] = sum; __syncthreads();
    for (int off = 1; off < 256; off <<= 1) {
        const unsigned int t = (tid >= off) ? s[tid - off] : 0u;
        __syncthreads();
        s[tid] += t;
        __syncthreads();
    }
    unsigned int run = bsum[b] + (s[tid] - sum);
#pragma unroll
    for (int k = 0; k < 4; ++k) { const int i = base + k; if (i < n) offs[i] = run; run += v[k]; }
}

// pos = cursor++ on offs (offs becomes "end"); tlist[pos] = t
__global__ __launch_bounds__(256) void scatter_kernel(const int* __restrict__ ac,
                                                      unsigned int* __restrict__ offs,
                                                      unsigned int* __restrict__ tlist, int T_) {
    int t = blockIdx.x * blockDim.x + threadIdx.x;
    const int stride = gridDim.x * blockDim.x;
    for (; t < T_; t += stride) {
        const unsigned int pos = atomicAdd(&offs[ac[t]], 1u);
        tlist[pos] = (unsigned int)t;
    }
}

// Process triangles in SORTED (tlist) order; write msg row i for sorted position i.
// Wide gather: each lane loads 16B (8 bf16); 8 lanes/row -> 8 rows per instruction,
// rows interleaved a0,b0,a1,b1,... so partner row = shfl_xor(.,8).
__global__ __launch_bounds__(256) void msg_sorted_kernel(
    const unsigned short* __restrict__ xtab, const float* __restrict__ Wmsg,
    const int* __restrict__ ab, const int* __restrict__ bc,
    const unsigned int* __restrict__ tlist, unsigned short* __restrict__ msg, int T_) {
    __shared__ unsigned short P[4][16 * 64];

    const int lane = threadIdx.x & 63;
    const int w    = threadIdx.x >> 6;

    bf16x8 bw[4][2];
    load_w_frags(Wmsg, lane, bw);

    const int wave   = (blockIdx.x * blockDim.x + threadIdx.x) >> 6;
    const int nwaves = (gridDim.x * blockDim.x) >> 6;
    const int groups = T_ >> 4;

    const int side = (lane >> 3) & 1;     // 0 = a-row, 1 = b-row
    const int cb   = (lane & 7) * 8;      // element block within row (8 bf16)
    const int tsub = lane >> 4;           // 0..3

    for (int g = wave; g < groups; g += nwaves) {
        const int bu = g << 4;
        const int t  = (int)tlist[bu + (lane & 15)];
        const int ia = ab[t];
        const int ib = bc[t];

        // ---- phase 1: 4 wide gathers (8 rows each) -> products -> swizzled LDS ----
#pragma unroll
        for (int ld = 0; ld < 4; ++ld) {
            const int ttl = ld * 4 + tsub;
            const int ea  = __shfl(ia, ttl, 64);
            const int eb  = __shfl(ib, ttl, 64);
            const int e   = side ? eb : ea;
            const uint4 v = *reinterpret_cast<const uint4*>(&xtab[(size_t)e * DD + cb]);
            uint4 o;
            o.x = (unsigned)__shfl_xor((int)v.x, 8, 64);
            o.y = (unsigned)__shfl_xor((int)v.y, 8, 64);
            o.z = (unsigned)__shfl_xor((int)v.z, 8, 64);
            o.w = (unsigned)__shfl_xor((int)v.w, 8, 64);
            uint4 pk;
            pk.x = pack2(bf2f(v.x & 0xffffu) * bf2f(o.x & 0xffffu),
                         bf2f(v.x >> 16)     * bf2f(o.x >> 16));
            pk.y = pack2(bf2f(v.y & 0xffffu) * bf2f(o.y & 0xffffu),
                         bf2f(v.y >> 16)     * bf2f(o.y >> 16));
            pk.z = pack2(bf2f(v.z & 0xffffu) * bf2f(o.z & 0xffffu),
                         bf2f(v.z >> 16)     * bf2f(o.z >> 16));
            pk.w = pack2(bf2f(v.w & 0xffffu) * bf2f(o.w & 0xffffu),
                         bf2f(v.w >> 16)     * bf2f(o.w >> 16));
            if (!side) {
                const int sw = (ttl & 7) << 3;
                *reinterpret_cast<uint4*>(&P[w][ttl * 64 + (cb ^ sw)]) = pk;
            }
        }

        // ---- phase 2: MFMA ----
        const int row = lane & 15;
        const int d0  = (lane >> 4) * 8;
        const int sw  = (row & 7) << 3;
        const bf16x8 a0 = *reinterpret_cast<const bf16x8*>(&P[w][row * 64 + ((d0)      ^ sw)]);
        const bf16x8 a1 = *reinterpret_cast<const bf16x8*>(&P[w][row * 64 + ((d0 + 32) ^ sw)]);

        f32x4 acc0 = {0.f, 0.f, 0.f, 0.f}, acc1 = acc0, acc2 = acc0, acc3 = acc0;
        MFMA8(a0, a1)

        // ---- epilogue: relu -> SEQUENTIAL bf16 row stores at sorted positions ----
        const int rb4 = (lane >> 4) * 4;
        const int cl  = lane & 15;
        const int odd = lane & 1;
#pragma unroll
        for (int r = 0; r < 4; ++r) {
            const int pos = bu + rb4 + r;
            const float o0 = fmaxf(acc0[r], 0.f), o1 = fmaxf(acc1[r], 0.f);
            const float o2 = fmaxf(acc2[r], 0.f), o3 = fmaxf(acc3[r], 0.f);
            const float n0 = __shfl_xor(o0, 1, 64), n1 = __shfl_xor(o1, 1, 64);
            const float n2 = __shfl_xor(o2, 1, 64), n3 = __shfl_xor(o3, 1, 64);
            const int base    = odd ? (cl - 1 + 32) : cl;
            const unsigned dA = odd ? pack2(n2, o2) : pack2(o0, n0);
            const unsigned dB = odd ? pack2(n3, o3) : pack2(o1, n1);
            unsigned int* dst = reinterpret_cast<unsigned int*>(&msg[(size_t)pos * DD + base]);
            dst[0] = dA;
            dst[8] = dB;
        }
    }
}

// per-edge CONTIGUOUS msg rows (fp32 accumulate) -> MFMA vs W_upd -> relu(x+u) -> out
__global__ __launch_bounds__(256) void gupd_seq_kernel(
    const unsigned short* __restrict__ xtab, const unsigned short* __restrict__ msg,
    const float* __restrict__ Wupd, const unsigned int* __restrict__ cnt,
    const unsigned int* __restrict__ offs_end, float* __restrict__ out, int E_) {
    __shared__ unsigned short P[4][16 * 64];
    __shared__ float U[4][16 * 65];

    const int lane = threadIdx.x & 63;
    const int w    = threadIdx.x >> 6;

    bf16x8 bw[4][2];
    load_w_frags(Wupd, lane, bw);

    const int wave   = (blockIdx.x * blockDim.x + threadIdx.x) >> 6;
    const int nwaves = (gridDim.x * blockDim.x) >> 6;
    const int groups = E_ >> 4;

    for (int g = wave; g < groups; g += nwaves) {
        const int bu  = g << 4;
        const int e16 = bu + (lane & 15);
        const int dg  = (int)cnt[e16];
        const int en  = (int)offs_end[e16];
        const int st  = en - dg;

#pragma unroll
        for (int tt = 0; tt < 16; ++tt) {
            const int dgt = __builtin_amdgcn_readlane(dg, tt);
            const int stt = __builtin_amdgcn_readlane(st, tt);
            float a = 0.f;
            for (int j = 0; j < dgt; ++j)
                a += bf2f(msg[(size_t)(stt + j) * DD + lane]);
            P[w][tt * 64 + (lane ^ ((tt & 7) << 3))] = f2bf(a);
        }

        const int row = lane & 15;
        const int d0  = (lane >> 4) * 8;
        const int sw  = (row & 7) << 3;
        const bf16x8 a0 = *reinterpret_cast<const bf16x8*>(&P[w][row * 64 + ((d0)      ^ sw)]);
        const bf16x8 a1 = *reinterpret_cast<const bf16x8*>(&P[w][row * 64 + ((d0 + 32) ^ sw)]);

        f32x4 acc0 = {0.f, 0.f, 0.f, 0.f}, acc1 = acc0, acc2 = acc0, acc3 = acc0;
        MFMA8(a0, a1)

        const int rb4 = (lane >> 4) * 4;
        const int cl  = lane & 15;
#pragma unroll
        for (int r = 0; r < 4; ++r) {
            U[w][(rb4 + r) * 65 + cl + 0]  = acc0[r];
            U[w][(rb4 + r) * 65 + cl + 16] = acc1[r];
            U[w][(rb4 + r) * 65 + cl + 32] = acc2[r];
            U[w][(rb4 + r) * 65 + cl + 48] = acc3[r];
        }

#pragma unroll
        for (int tt = 0; tt < 16; ++tt) {
            const int e   = bu + tt;
            const float x = bf2f(xtab[(size_t)e * DD + lane]);
            out[(size_t)e * DD + lane] = fmaxf(x + U[w][tt * 65 + lane], 0.f);
        }
    }
}

// ---------- tier 2: pk-bf16 atomic path ----------
__global__ __launch_bounds__(256) void tri_fast(
    const unsigned short* __restrict__ xtab, const float* __restrict__ Wmsg,
    const int* __restrict__ ab, const int* __restrict__ bc,
    const int* __restrict__ ac, unsigned short* __restrict__ aggbf, int T_) {
    __shared__ unsigned short P[4][16 * 64];
    const int lane = threadIdx.x & 63;
    const int w    = threadIdx.x >> 6;
    bf16x8 bw[4][2];
    load_w_frags(Wmsg, lane, bw);
    const int wave   = (blockIdx.x * blockDim.x + threadIdx.x) >> 6;
    const int nwaves = (gridDim.x * blockDim.x) >> 6;
    const int groups = T_ >> 4;
    for (int g = wave; g < groups; g += nwaves) {
        const int bu  = g << 4;
        const int t16 = bu + (lane & 15);
        const int ia = ab[t16], ib = bc[t16], ic = ac[t16];
#pragma unroll
        for (int tt = 0; tt < 16; ++tt) {
            const int ea = __builtin_amdgcn_readlane(ia, tt);
            const int eb = __builtin_amdgcn_readlane(ib, tt);
            const float xa = bf2f(xtab[(size_t)ea * DD + lane]);
            const float xb = bf2f(xtab[(size_t)eb * DD + lane]);
            P[w][tt * 64 + (lane ^ ((tt & 7) << 3))] = f2bf(xa * xb);
        }
        const int row = lane & 15;
        const int d0  = (lane >> 4) * 8;
        const int sw  = (row & 7) << 3;
        const bf16x8 a0 = *reinterpret_cast<const bf16x8*>(&P[w][row * 64 + ((d0)      ^ sw)]);
        const bf16x8 a1 = *reinterpret_cast<const bf16x8*>(&P[w][row * 64 + ((d0 + 32) ^ sw)]);
        f32x4 acc0 = {0.f, 0.f, 0.f, 0.f}, acc1 = acc0, acc2 = acc0, acc3 = acc0;
        MFMA8(a0, a1)
        const int rb4 = (lane >> 4) * 4;
        const int cl  = lane & 15;
        const int odd = lane & 1;
#pragma unroll
        for (int r = 0; r < 4; ++r) {
            const int ec = __shfl(ic, rb4 + r, 64);
            const float o0 = fmaxf(acc0[r], 0.f), o1 = fmaxf(acc1[r], 0.f);
            const float o2 = fmaxf(acc2[r], 0.f), o3 = fmaxf(acc3[r], 0.f);
            const float n0 = __shfl_xor(o0, 1, 64), n1 = __shfl_xor(o1, 1, 64);
            const float n2 = __shfl_xor(o2, 1, 64), n3 = __shfl_xor(o3, 1, 64);
            const int base      = odd ? (cl - 1 + 32) : cl;
            const unsigned dA   = odd ? pack2(n2, o2) : pack2(o0, n0);
            const unsigned dB   = odd ? pack2(n3, o3) : pack2(o1, n1);
            unsigned short* dst = &aggbf[(size_t)ec * DD + base];
            pk_atomic_add_bf16(dst + 0,  dA);
            pk_atomic_add_bf16(dst + 16, dB);
        }
    }
}

__global__ __launch_bounds__(256) void upd_fast(
    const unsigned short* __restrict__ xtab, const unsigned short* __restrict__ aggbf,
    const float* __restrict__ Wupd, float* __restrict__ out, int E_) {
    __shared__ unsigned short P[4][16 * 64];
    __shared__ float U[4][16 * 65];
    const int lane = threadIdx.x & 63;
    const int w    = threadIdx.x >> 6;
    bf16x8 bw[4][2];
    load_w_frags(Wupd, lane, bw);
    const int wave   = (blockIdx.x * blockDim.x + threadIdx.x) >> 6;
    const int nwaves = (gridDim.x * blockDim.x) >> 6;
    const int groups = E_ >> 4;
    for (int g = wave; g < groups; g += nwaves) {
        const int bu = g << 4;
#pragma unroll
        for (int tt = 0; tt < 16; ++tt)
            P[w][tt * 64 + (lane ^ ((tt & 7) << 3))] = aggbf[(size_t)(bu + tt) * DD + lane];
        const int row = lane & 15;
        const int d0  = (lane >> 4) * 8;
        const int sw  = (row & 7) << 3;
        const bf16x8 a0 = *reinterpret_cast<const bf16x8*>(&P[w][row * 64 + ((d0)      ^ sw)]);
        const bf16x8 a1 = *reinterpret_cast<const bf16x8*>(&P[w][row * 64 + ((d0 + 32) ^ sw)]);
        f32x4 acc0 = {0.f, 0.f, 0.f, 0.f}, acc1 = acc0, acc2 = acc0, acc3 = acc0;
        MFMA8(a0, a1)
        const int rb4 = (lane >> 4) * 4;
        const int cl  = lane & 15;
#pragma unroll
        for (int r = 0; r < 4; ++r) {
            U[w][(rb4 + r) * 65 + cl + 0]  = acc0[r];
            U[w][(rb4 + r) * 65 + cl + 16] = acc1[r];
            U[w][(rb4 + r) * 65 + cl + 32] = acc2[r];
            U[w][(rb4 + r) * 65 + cl + 48] = acc3[r];
        }
#pragma unroll
        for (int tt = 0; tt < 16; ++tt) {
            const int e   = bu + tt;
            const float x = bf2f(xtab[(size_t)e * DD + lane]);
            out[(size_t)e * DD + lane] = fmaxf(x + U[w][tt * 65 + lane], 0.f);
        }
    }
}

// ---------- tier 1: fully general fallback ----------
__global__ __launch_bounds__(256) void tri_fb(
    const float* __restrict__ feat, const float* __restrict__ emb,
    const float* __restrict__ Wmsg, const int* __restrict__ rel,
    const int* __restrict__ ab, const int* __restrict__ bc,
    const int* __restrict__ ac, float* __restrict__ agg, int T_) {
    __shared__ unsigned short P[4][16 * 64];
    const int lane = threadIdx.x & 63;
    const int w    = threadIdx.x >> 6;
    bf16x8 bw[4][2];
    load_w_frags(Wmsg, lane, bw);
    const int wave   = (blockIdx.x * blockDim.x + threadIdx.x) >> 6;
    const int nwaves = (gridDim.x * blockDim.x) >> 6;
    const int groups = (T_ + 15) >> 4;
    for (int g = wave; g < groups; g += nwaves) {
        const int bu = __builtin_amdgcn_readfirstlane(g << 4);
#pragma unroll 4
        for (int tt = 0; tt < 16; ++tt) {
            const int t = bu + tt;
            float p = 0.f;
            if (t < T_) {
                const int ea = ab[t], eb = bc[t];
                const float xa = feat[ea * DD + lane] + emb[rel[ea] * DD + lane];
                const float xb = feat[eb * DD + lane] + emb[rel[eb] * DD + lane];
                p = xa * xb;
            }
            P[w][tt * 64 + (lane ^ ((tt & 7) << 3))] = f2bf(p);
        }
        const int row = lane & 15;
        const int d0  = (lane >> 4) * 8;
        const int sw  = (row & 7) << 3;
        const bf16x8 a0 = *reinterpret_cast<const bf16x8*>(&P[w][row * 64 + ((d0)      ^ sw)]);
        const bf16x8 a1 = *reinterpret_cast<const bf16x8*>(&P[w][row * 64 + ((d0 + 32) ^ sw)]);
        f32x4 acc0 = {0.f, 0.f, 0.f, 0.f}, acc1 = acc0, acc2 = acc0, acc3 = acc0;
        MFMA8(a0, a1)
        const int rb4 = (lane >> 4) * 4;
        const int cl  = lane & 15;
#pragma unroll
        for (int r = 0; r < 4; ++r) {
            const int t = bu + rb4 + r;
            if (t < T_) {
                float* dst = &agg[(size_t)ac[t] * DD + cl];
                atomicAdd(dst + 0,  fmaxf(acc0[r], 0.f));
                atomicAdd(dst + 16, fmaxf(acc1[r], 0.f));
                atomicAdd(dst + 32, fmaxf(acc2[r], 0.f));
                atomicAdd(dst + 48, fmaxf(acc3[r], 0.f));
            }
        }
    }
}

__global__ __launch_bounds__(256) void upd_fb(
    const float* __restrict__ feat, const float* __restrict__ emb,
    const float* __restrict__ Wupd, const int* __restrict__ rel,
    float* __restrict__ agg_out, int E_) {
    __shared__ unsigned short P[4][16 * 64];
    __shared__ float U[4][16 * 65];
    const int lane = threadIdx.x & 63;
    const int w    = threadIdx.x >> 6;
    bf16x8 bw[4][2];
    load_w_frags(Wupd, lane, bw);
    const int wave   = (blockIdx.x * blockDim.x + threadIdx.x) >> 6;
    const int nwaves = (gridDim.x * blockDim.x) >> 6;
    const int groups = (E_ + 15) >> 4;
    for (int g = wave; g < groups; g += nwaves) {
        const int bu = __builtin_amdgcn_readfirstlane(g << 4);
#pragma unroll 4
        for (int tt = 0; tt < 16; ++tt) {
            const int e = bu + tt;
            const float v = (e < E_) ? agg_out[(size_t)e * DD + lane] : 0.f;
            P[w][tt * 64 + (lane ^ ((tt & 7) << 3))] = f2bf(v);
        }
        const int row = lane & 15;
        const int d0  = (lane >> 4) * 8;
        const int sw  = (row & 7) << 3;
        const bf16x8 a0 = *reinterpret_cast<const bf16x8*>(&P[w][row * 64 + ((d0)      ^ sw)]);
        const bf16x8 a1 = *reinterpret_cast<const bf16x8*>(&P[w][row * 64 + ((d0 + 32) ^ sw)]);
        f32x4 acc0 = {0.f, 0.f, 0.f, 0.f}, acc1 = acc0, acc2 = acc0, acc3 = acc0;
        MFMA8(a0, a1)
        const int rb4 = (lane >> 4) * 4;
        const int cl  = lane & 15;
#pragma unroll
        for (int r = 0; r < 4; ++r) {
            U[w][(rb4 + r) * 65 + cl + 0]  = acc0[r];
            U[w][(rb4 + r) * 65 + cl + 16] = acc1[r];
            U[w][(rb4 + r) * 65 + cl + 32] = acc2[r];
            U[w][(rb4 + r) * 65 + cl + 48] = acc3[r];
        }
#pragma unroll 4
        for (int tt = 0; tt < 16; ++tt) {
            const int e = bu + tt;
            if (e < E_) {
                const float x = feat[(size_t)e * DD + lane] + emb[rel[e] * DD + lane];
                agg_out[(size_t)e * DD + lane] = fmaxf(x + U[w][tt * 65 + lane], 0.f);
            }
        }
    }
}

extern "C" void kernel_launch(void* const* d_in, const int* in_sizes, int n_in,
                              void* d_out, int out_size, void* d_ws, size_t ws_size,
                              hipStream_t stream) {
    const float* feat = (const float*)d_in[0];
    const float* emb  = (const float*)d_in[1];
    const float* Wmsg = (const float*)d_in[2];
    const float* Wupd = (const float*)d_in[3];
    const int*   rel  = (const int*)d_in[4];
    const int*   ab   = (const int*)d_in[5];
    const int*   bc   = (const int*)d_in[6];
    const int*   ac   = (const int*)d_in[7];

    const int E_ = in_sizes[0] / DD;
    const int T_ = in_sizes[5];

    const size_t xbytes   = (size_t)E_ * DD * sizeof(unsigned short);   // 128 MB
    const size_t msgbytes = (size_t)T_ * DD * sizeof(unsigned short);   // 256 MB
    const size_t tlbytes  = (size_t)T_ * sizeof(unsigned int);
    const size_t cbytes   = ((size_t)(E_ + 1) * sizeof(unsigned int) + 255u) & ~(size_t)255u;
    const int    nscan    = E_ + 1;
    const int    nblk     = (nscan + SCAN_CH - 1) / SCAN_CH;
    const size_t need3    = xbytes + msgbytes + tlbytes + 2 * cbytes + 4096 * sizeof(unsigned int);

    const bool aligned16 = ((T_ & 15) == 0) && ((E_ & 15) == 0);
    const bool fast3 = aligned16 && (nblk <= 1024) && (ws_size >= need3);
    const bool fast2 = aligned16 && (ws_size >= 2 * xbytes);

    if (fast3) {
        char* p = (char*)d_ws;
        unsigned short* xtab  = (unsigned short*)p;            p += xbytes;
        unsigned short* msg   = (unsigned short*)p;            p += msgbytes;
        unsigned int*   tlist = (unsigned int*)p;              p += tlbytes;
        unsigned int*   cnt   = (unsigned int*)p;              p += cbytes;
        unsigned int*   offs  = (unsigned int*)p;              p += cbytes;
        unsigned int*   bsum  = (unsigned int*)p;

        hipMemsetAsync(cnt, 0, (size_t)nscan * sizeof(unsigned int), stream);
        hipLaunchKernelGGL(xprep_kernel, dim3(2048), dim3(256), 0, stream,
                           (const float4*)feat, (const float4*)emb, rel, xtab, E_ * 16);
        hipLaunchKernelGGL(hist_kernel, dim3(2048), dim3(256), 0, stream, ac, cnt, T_);
        hipLaunchKernelGGL(scanA_kernel, dim3(nblk), dim3(256), 0, stream, cnt, bsum, nscan);
        hipLaunchKernelGGL(scanB_kernel, dim3(1), dim3(1024), 0, stream, bsum, nblk);
        hipLaunchKernelGGL(scanC_kernel, dim3(nblk), dim3(256), 0, stream, cnt, bsum, offs, nscan);
        hipLaunchKernelGGL(scatter_kernel, dim3(2048), dim3(256), 0, stream, ac, offs, tlist, T_);
        hipLaunchKernelGGL(msg_sorted_kernel, dim3(2048), dim3(256), 0, stream,
                           xtab, Wmsg, ab, bc, tlist, msg, T_);
        hipLaunchKernelGGL(gupd_seq_kernel, dim3(2048), dim3(256), 0, stream,
                           xtab, msg, Wupd, cnt, offs, (float*)d_out, E_);
    } else if (fast2) {
        unsigned short* xtab  = (unsigned short*)d_ws;
        unsigned short* aggbf = (unsigned short*)((char*)d_ws + xbytes);
        hipMemsetAsync(aggbf, 0, xbytes, stream);
        hipLaunchKernelGGL(xprep_kernel, dim3(2048), dim3(256), 0, stream,
                           (const float4*)feat, (const float4*)emb, rel, xtab, E_ * 16);
        hipLaunchKernelGGL(tri_fast, dim3(2048), dim3(256), 0, stream,
                           xtab, Wmsg, ab, bc, ac, aggbf, T_);
        hipLaunchKernelGGL(upd_fast, dim3(2048), dim3(256), 0, stream,
                           xtab, aggbf, Wupd, (float*)d_out, E_);
    } else {
        float* agg = (float*)d_out;
        hipMemsetAsync(d_out, 0, (size_t)E_ * DD * sizeof(float), stream);
        hipLaunchKernelGGL(tri_fb, dim3(2048), dim3(256), 0, stream,
                           feat, emb, Wmsg, rel, ab, bc, ac, agg, T_);
        hipLaunchKernelGGL(upd_fb, dim3(2048), dim3(256), 0, stream,
                           feat, emb, Wupd, rel, agg, E_);
    }
}

// Round 6
// 601.210 us; speedup vs baseline: 1.4345x; 1.4345x over previous
//
#include <hip/hip_runtime.h>
#include <hip/hip_bf16.h>

#define DD 64

typedef __attribute__((ext_vector_type(8))) short bf16x8;
typedef __attribute__((ext_vector_type(4))) float f32x4;

__device__ __forceinline__ unsigned short f2bf(float f) {
    unsigned int u = __float_as_uint(f);
    unsigned int r = (u + 0x7fffu + ((u >> 16) & 1u)) >> 16;   // RNE
    return (unsigned short)r;
}
__device__ __forceinline__ float bf2f(unsigned short u) {
    return __uint_as_float((unsigned int)u << 16);
}
__device__ __forceinline__ unsigned int pack2(float lo, float hi) {
    return (unsigned int)f2bf(lo) | ((unsigned int)f2bf(hi) << 16);
}
__device__ __forceinline__ void pk_atomic_add_bf16(unsigned short* addr, unsigned int data) {
    asm volatile("global_atomic_pk_add_bf16 %0, %1, off" :: "v"(addr), "v"(data) : "memory");
}

// B frag for 16x16x32: lane l holds B[k = ks*32 + (l>>4)*8 + b][col = nt*16 + (l&15)]
__device__ __forceinline__ void load_w_frags(const float* __restrict__ W, int lane,
                                             bf16x8 bw[4][2]) {
    const int kl = (lane >> 4) * 8;
    const int cl = lane & 15;
#pragma unroll
    for (int nt = 0; nt < 4; ++nt)
#pragma unroll
        for (int ks = 0; ks < 2; ++ks)
#pragma unroll
            for (int b = 0; b < 8; ++b)
                bw[nt][ks][b] = (short)f2bf(W[(ks * 32 + kl + b) * DD + nt * 16 + cl]);
}

#define MFMA8(A0, A1)                                                          \
    acc0 = __builtin_amdgcn_mfma_f32_16x16x32_bf16(A0, bw[0][0], acc0, 0, 0, 0); \
    acc0 = __builtin_amdgcn_mfma_f32_16x16x32_bf16(A1, bw[0][1], acc0, 0, 0, 0); \
    acc1 = __builtin_amdgcn_mfma_f32_16x16x32_bf16(A0, bw[1][0], acc1, 0, 0, 0); \
    acc1 = __builtin_amdgcn_mfma_f32_16x16x32_bf16(A1, bw[1][1], acc1, 0, 0, 0); \
    acc2 = __builtin_amdgcn_mfma_f32_16x16x32_bf16(A0, bw[2][0], acc2, 0, 0, 0); \
    acc2 = __builtin_amdgcn_mfma_f32_16x16x32_bf16(A1, bw[2][1], acc2, 0, 0, 0); \
    acc3 = __builtin_amdgcn_mfma_f32_16x16x32_bf16(A0, bw[3][0], acc3, 0, 0, 0); \
    acc3 = __builtin_amdgcn_mfma_f32_16x16x32_bf16(A1, bw[3][1], acc3, 0, 0, 0);

// ---------- x-table prep ----------
__global__ __launch_bounds__(256) void xprep_kernel(
    const float4* __restrict__ feat4, const float4* __restrict__ emb4,
    const int* __restrict__ rel, unsigned short* __restrict__ xtab, int n4) {
    int i = blockIdx.x * blockDim.x + threadIdx.x;
    const int stride = gridDim.x * blockDim.x;
    for (; i < n4; i += stride) {
        const int e  = i >> 4;
        const int re = rel[e];
        const float4 f = feat4[i];
        const float4 g = emb4[re * 16 + (i & 15)];
        ushort4 o;
        o.x = f2bf(f.x + g.x); o.y = f2bf(f.y + g.y);
        o.z = f2bf(f.z + g.z); o.w = f2bf(f.w + g.w);
        *reinterpret_cast<ushort4*>(&xtab[(size_t)i * 4]) = o;
    }
}

// ---------- tier 2 improved: wide gathers, 2 tiles/iteration, pk-bf16 atomics ----------

// PROD_STORE: v holds 8 bf16 of row (a or b side); partner via shfl_xor(.,8);
// a-side lanes write the product chunk into the swizzled P tile.
#define PROD_STORE(v, tile, ld)                                                      \
    {                                                                                \
        uint4 o;                                                                     \
        o.x = (unsigned)__shfl_xor((int)(v).x, 8, 64);                               \
        o.y = (unsigned)__shfl_xor((int)(v).y, 8, 64);                               \
        o.z = (unsigned)__shfl_xor((int)(v).z, 8, 64);                               \
        o.w = (unsigned)__shfl_xor((int)(v).w, 8, 64);                               \
        if (!side) {                                                                 \
            uint4 pk;                                                                \
            pk.x = pack2(bf2f((v).x & 0xffffu) * bf2f(o.x & 0xffffu),                \
                         bf2f((v).x >> 16)     * bf2f(o.x >> 16));                   \
            pk.y = pack2(bf2f((v).y & 0xffffu) * bf2f(o.y & 0xffffu),                \
                         bf2f((v).y >> 16)     * bf2f(o.y >> 16));                   \
            pk.z = pack2(bf2f((v).z & 0xffffu) * bf2f(o.z & 0xffffu),                \
                         bf2f((v).z >> 16)     * bf2f(o.z >> 16));                   \
            pk.w = pack2(bf2f((v).w & 0xffffu) * bf2f(o.w & 0xffffu),                \
                         bf2f((v).w >> 16)     * bf2f(o.w >> 16));                   \
            const int ttl = (ld) * 4 + tsub;                                         \
            const int swz = (ttl & 7) << 3;                                          \
            *reinterpret_cast<uint4*>(&P[w][(tile) * 1024 + ttl * 64 + (cb ^ swz)]) = pk; \
        }                                                                            \
    }

// TILE_TAIL: fragments from P[tile] -> 8 MFMA -> relu -> pk-bf16 atomic scatter.
#define TILE_TAIL(tile, icv)                                                         \
    {                                                                                \
        const int row = lane & 15;                                                   \
        const int d0  = (lane >> 4) * 8;                                             \
        const int swz = (row & 7) << 3;                                              \
        const bf16x8 a0 = *reinterpret_cast<const bf16x8*>(                          \
            &P[w][(tile) * 1024 + row * 64 + ((d0) ^ swz)]);                         \
        const bf16x8 a1 = *reinterpret_cast<const bf16x8*>(                          \
            &P[w][(tile) * 1024 + row * 64 + ((d0 + 32) ^ swz)]);                    \
        f32x4 acc0 = {0.f, 0.f, 0.f, 0.f}, acc1 = acc0, acc2 = acc0, acc3 = acc0;    \
        MFMA8(a0, a1)                                                                \
        const int rb4 = (lane >> 4) * 4;                                             \
        const int cl  = lane & 15;                                                   \
        const int odd = lane & 1;                                                    \
        _Pragma("unroll")                                                            \
        for (int r = 0; r < 4; ++r) {                                                \
            const int ec = __shfl((icv), rb4 + r, 64);                               \
            const float o0 = fmaxf(acc0[r], 0.f), o1 = fmaxf(acc1[r], 0.f);          \
            const float o2 = fmaxf(acc2[r], 0.f), o3 = fmaxf(acc3[r], 0.f);          \
            const float n0 = __shfl_xor(o0, 1, 64), n1 = __shfl_xor(o1, 1, 64);      \
            const float n2 = __shfl_xor(o2, 1, 64), n3 = __shfl_xor(o3, 1, 64);      \
            const int base      = odd ? (cl - 1 + 32) : cl;                          \
            const unsigned dA   = odd ? pack2(n2, o2) : pack2(o0, n0);               \
            const unsigned dB   = odd ? pack2(n3, o3) : pack2(o1, n1);               \
            unsigned short* dst = &aggbf[(size_t)ec * DD + base];                    \
            pk_atomic_add_bf16(dst + 0,  dA);                                        \
            pk_atomic_add_bf16(dst + 16, dB);                                        \
        }                                                                            \
    }

__global__ __launch_bounds__(256) void tri_fast2(
    const unsigned short* __restrict__ xtab, const float* __restrict__ Wmsg,
    const int* __restrict__ ab, const int* __restrict__ bc,
    const int* __restrict__ ac, unsigned short* __restrict__ aggbf, int T_) {
    __shared__ unsigned short P[4][2 * 16 * 64];   // 16 KB/block, per-wave slices

    const int lane = threadIdx.x & 63;
    const int w    = threadIdx.x >> 6;

    bf16x8 bw[4][2];
    load_w_frags(Wmsg, lane, bw);

    const int wave   = (blockIdx.x * blockDim.x + threadIdx.x) >> 6;
    const int nwaves = (gridDim.x * blockDim.x) >> 6;
    const int npairs = T_ >> 5;   // launcher guarantees T_ % 32 == 0

    const int side = (lane >> 3) & 1;    // 0 = a-row, 1 = b-row
    const int cb   = (lane & 7) * 8;     // 8-elem block within row
    const int tsub = lane >> 4;          // 0..3
    const int* __restrict__ esrc = side ? bc : ab;

    for (int gp = wave; gp < npairs; gp += nwaves) {
        const int bu = gp << 5;

        // per-lane row indices: broadcast-coalesced 4B loads (64B segments)
        const int eA0 = esrc[bu + 0 + tsub],  eA1 = esrc[bu + 4 + tsub];
        const int eA2 = esrc[bu + 8 + tsub],  eA3 = esrc[bu + 12 + tsub];
        const int eB0 = esrc[bu + 16 + tsub], eB1 = esrc[bu + 20 + tsub];
        const int eB2 = esrc[bu + 24 + tsub], eB3 = esrc[bu + 28 + tsub];
        const int icA = ac[bu + (lane & 15)];
        const int icB = ac[bu + 16 + (lane & 15)];

        // 8 independent wide gathers (8 rows / instruction, 8 KB in flight)
        const uint4 vA0 = *reinterpret_cast<const uint4*>(&xtab[(size_t)eA0 * DD + cb]);
        const uint4 vA1 = *reinterpret_cast<const uint4*>(&xtab[(size_t)eA1 * DD + cb]);
        const uint4 vA2 = *reinterpret_cast<const uint4*>(&xtab[(size_t)eA2 * DD + cb]);
        const uint4 vA3 = *reinterpret_cast<const uint4*>(&xtab[(size_t)eA3 * DD + cb]);
        const uint4 vB0 = *reinterpret_cast<const uint4*>(&xtab[(size_t)eB0 * DD + cb]);
        const uint4 vB1 = *reinterpret_cast<const uint4*>(&xtab[(size_t)eB1 * DD + cb]);
        const uint4 vB2 = *reinterpret_cast<const uint4*>(&xtab[(size_t)eB2 * DD + cb]);
        const uint4 vB3 = *reinterpret_cast<const uint4*>(&xtab[(size_t)eB3 * DD + cb]);

        PROD_STORE(vA0, 0, 0) PROD_STORE(vA1, 0, 1)
        PROD_STORE(vA2, 0, 2) PROD_STORE(vA3, 0, 3)
        PROD_STORE(vB0, 1, 0) PROD_STORE(vB1, 1, 1)
        PROD_STORE(vB2, 1, 2) PROD_STORE(vB3, 1, 3)

        TILE_TAIL(0, icA)
        TILE_TAIL(1, icB)
    }
}

// ---------- tier 2: update pass (wide phase-1) ----------
__global__ __launch_bounds__(256) void upd_fast(
    const unsigned short* __restrict__ xtab, const unsigned short* __restrict__ aggbf,
    const float* __restrict__ Wupd, float* __restrict__ out, int E_) {
    __shared__ unsigned short P[4][16 * 64];
    __shared__ float U[4][16 * 65];

    const int lane = threadIdx.x & 63;
    const int w    = threadIdx.x >> 6;

    bf16x8 bw[4][2];
    load_w_frags(Wupd, lane, bw);

    const int wave   = (blockIdx.x * blockDim.x + threadIdx.x) >> 6;
    const int nwaves = (gridDim.x * blockDim.x) >> 6;
    const int groups = E_ >> 4;   // E_ % 16 == 0 guaranteed by launcher

    for (int g = wave; g < groups; g += nwaves) {
        const int bu = g << 4;

        // wide contiguous tile load: 2 x 16B/lane, swizzled ds_write_b128
#pragma unroll
        for (int half = 0; half < 2; ++half) {
            const int flat = half * 512 + lane * 8;
            const int row  = flat >> 6;
            const int colb = flat & 63;
            const uint4 v = *reinterpret_cast<const uint4*>(&aggbf[(size_t)bu * DD + flat]);
            *reinterpret_cast<uint4*>(&P[w][row * 64 + (colb ^ ((row & 7) << 3))]) = v;
        }

        const int row = lane & 15;
        const int d0  = (lane >> 4) * 8;
        const int sw  = (row & 7) << 3;
        const bf16x8 a0 = *reinterpret_cast<const bf16x8*>(&P[w][row * 64 + ((d0)      ^ sw)]);
        const bf16x8 a1 = *reinterpret_cast<const bf16x8*>(&P[w][row * 64 + ((d0 + 32) ^ sw)]);

        f32x4 acc0 = {0.f, 0.f, 0.f, 0.f}, acc1 = acc0, acc2 = acc0, acc3 = acc0;
        MFMA8(a0, a1)

        const int rb4 = (lane >> 4) * 4;
        const int cl  = lane & 15;
#pragma unroll
        for (int r = 0; r < 4; ++r) {
            U[w][(rb4 + r) * 65 + cl + 0]  = acc0[r];
            U[w][(rb4 + r) * 65 + cl + 16] = acc1[r];
            U[w][(rb4 + r) * 65 + cl + 32] = acc2[r];
            U[w][(rb4 + r) * 65 + cl + 48] = acc3[r];
        }

#pragma unroll
        for (int tt = 0; tt < 16; ++tt) {
            const int e   = bu + tt;
            const float x = bf2f(xtab[(size_t)e * DD + lane]);
            out[(size_t)e * DD + lane] = fmaxf(x + U[w][tt * 65 + lane], 0.f);
        }
    }
}

// ---------- tier 1: fully general fallback ----------
__global__ __launch_bounds__(256) void tri_fb(
    const float* __restrict__ feat, const float* __restrict__ emb,
    const float* __restrict__ Wmsg, const int* __restrict__ rel,
    const int* __restrict__ ab, const int* __restrict__ bc,
    const int* __restrict__ ac, float* __restrict__ agg, int T_) {
    __shared__ unsigned short P[4][16 * 64];
    const int lane = threadIdx.x & 63;
    const int w    = threadIdx.x >> 6;
    bf16x8 bw[4][2];
    load_w_frags(Wmsg, lane, bw);
    const int wave   = (blockIdx.x * blockDim.x + threadIdx.x) >> 6;
    const int nwaves = (gridDim.x * blockDim.x) >> 6;
    const int groups = (T_ + 15) >> 4;
    for (int g = wave; g < groups; g += nwaves) {
        const int bu = __builtin_amdgcn_readfirstlane(g << 4);
#pragma unroll 4
        for (int tt = 0; tt < 16; ++tt) {
            const int t = bu + tt;
            float p = 0.f;
            if (t < T_) {
                const int ea = ab[t], eb = bc[t];
                const float xa = feat[ea * DD + lane] + emb[rel[ea] * DD + lane];
                const float xb = feat[eb * DD + lane] + emb[rel[eb] * DD + lane];
                p = xa * xb;
            }
            P[w][tt * 64 + (lane ^ ((tt & 7) << 3))] = f2bf(p);
        }
        const int row = lane & 15;
        const int d0  = (lane >> 4) * 8;
        const int sw  = (row & 7) << 3;
        const bf16x8 a0 = *reinterpret_cast<const bf16x8*>(&P[w][row * 64 + ((d0)      ^ sw)]);
        const bf16x8 a1 = *reinterpret_cast<const bf16x8*>(&P[w][row * 64 + ((d0 + 32) ^ sw)]);
        f32x4 acc0 = {0.f, 0.f, 0.f, 0.f}, acc1 = acc0, acc2 = acc0, acc3 = acc0;
        MFMA8(a0, a1)
        const int rb4 = (lane >> 4) * 4;
        const int cl  = lane & 15;
#pragma unroll
        for (int r = 0; r < 4; ++r) {
            const int t = bu + rb4 + r;
            if (t < T_) {
                float* dst = &agg[(size_t)ac[t] * DD + cl];
                atomicAdd(dst + 0,  fmaxf(acc0[r], 0.f));
                atomicAdd(dst + 16, fmaxf(acc1[r], 0.f));
                atomicAdd(dst + 32, fmaxf(acc2[r], 0.f));
                atomicAdd(dst + 48, fmaxf(acc3[r], 0.f));
            }
        }
    }
}

__global__ __launch_bounds__(256) void upd_fb(
    const float* __restrict__ feat, const float* __restrict__ emb,
    const float* __restrict__ Wupd, const int* __restrict__ rel,
    float* __restrict__ agg_out, int E_) {
    __shared__ unsigned short P[4][16 * 64];
    __shared__ float U[4][16 * 65];
    const int lane = threadIdx.x & 63;
    const int w    = threadIdx.x >> 6;
    bf16x8 bw[4][2];
    load_w_frags(Wupd, lane, bw);
    const int wave   = (blockIdx.x * blockDim.x + threadIdx.x) >> 6;
    const int nwaves = (gridDim.x * blockDim.x) >> 6;
    const int groups = (E_ + 15) >> 4;
    for (int g = wave; g < groups; g += nwaves) {
        const int bu = __builtin_amdgcn_readfirstlane(g << 4);
#pragma unroll 4
        for (int tt = 0; tt < 16; ++tt) {
            const int e = bu + tt;
            const float v = (e < E_) ? agg_out[(size_t)e * DD + lane] : 0.f;
            P[w][tt * 64 + (lane ^ ((tt & 7) << 3))] = f2bf(v);
        }
        const int row = lane & 15;
        const int d0  = (lane >> 4) * 8;
        const int sw  = (row & 7) << 3;
        const bf16x8 a0 = *reinterpret_cast<const bf16x8*>(&P[w][row * 64 + ((d0)      ^ sw)]);
        const bf16x8 a1 = *reinterpret_cast<const bf16x8*>(&P[w][row * 64 + ((d0 + 32) ^ sw)]);
        f32x4 acc0 = {0.f, 0.f, 0.f, 0.f}, acc1 = acc0, acc2 = acc0, acc3 = acc0;
        MFMA8(a0, a1)
        const int rb4 = (lane >> 4) * 4;
        const int cl  = lane & 15;
#pragma unroll
        for (int r = 0; r < 4; ++r) {
            U[w][(rb4 + r) * 65 + cl + 0]  = acc0[r];
            U[w][(rb4 + r) * 65 + cl + 16] = acc1[r];
            U[w][(rb4 + r) * 65 + cl + 32] = acc2[r];
            U[w][(rb4 + r) * 65 + cl + 48] = acc3[r];
        }
#pragma unroll 4
        for (int tt = 0; tt < 16; ++tt) {
            const int e = bu + tt;
            if (e < E_) {
                const float x = feat[(size_t)e * DD + lane] + emb[rel[e] * DD + lane];
                agg_out[(size_t)e * DD + lane] = fmaxf(x + U[w][tt * 65 + lane], 0.f);
            }
        }
    }
}

extern "C" void kernel_launch(void* const* d_in, const int* in_sizes, int n_in,
                              void* d_out, int out_size, void* d_ws, size_t ws_size,
                              hipStream_t stream) {
    const float* feat = (const float*)d_in[0];
    const float* emb  = (const float*)d_in[1];
    const float* Wmsg = (const float*)d_in[2];
    const float* Wupd = (const float*)d_in[3];
    const int*   rel  = (const int*)d_in[4];
    const int*   ab   = (const int*)d_in[5];
    const int*   bc   = (const int*)d_in[6];
    const int*   ac   = (const int*)d_in[7];

    const int E_ = in_sizes[0] / DD;
    const int T_ = in_sizes[5];

    const size_t xbytes = (size_t)E_ * DD * sizeof(unsigned short);   // 128 MB
    const bool fast = (ws_size >= 2 * xbytes) && ((T_ & 31) == 0) && ((E_ & 15) == 0);

    if (fast) {
        unsigned short* xtab  = (unsigned short*)d_ws;
        unsigned short* aggbf = (unsigned short*)((char*)d_ws + xbytes);
        hipMemsetAsync(aggbf, 0, xbytes, stream);
        hipLaunchKernelGGL(xprep_kernel, dim3(2048), dim3(256), 0, stream,
                           (const float4*)feat, (const float4*)emb, rel, xtab, E_ * 16);
        hipLaunchKernelGGL(tri_fast2, dim3(2048), dim3(256), 0, stream,
                           xtab, Wmsg, ab, bc, ac, aggbf, T_);
        hipLaunchKernelGGL(upd_fast, dim3(2048), dim3(256), 0, stream,
                           xtab, aggbf, Wupd, (float*)d_out, E_);
    } else {
        float* agg = (float*)d_out;
        hipMemsetAsync(d_out, 0, (size_t)E_ * DD * sizeof(float), stream);
        hipLaunchKernelGGL(tri_fb, dim3(2048), dim3(256), 0, stream,
                           feat, emb, Wmsg, rel, ab, bc, ac, agg, T_);
        hipLaunchKernelGGL(upd_fb, dim3(2048), dim3(256), 0, stream,
                           feat, emb, Wupd, rel, agg, E_);
    }
}